// Round 7
// baseline (1196.988 us; speedup 1.0000x reference)
//
#include <hip/hip_runtime.h>

// Problem constants (match reference)
#define FQ 8
#define NSEQ 2
#define BQ 4096
#define LQ 50
#define VQ 100000
#define EQ 64
#define NPAIR 28
#define NIDXF (BQ * LQ)        // 204800 incidences per seq field
#define SLAB_ROWS 200
#define NSLAB 500              // 500 * 200 = 100000 = VQ
#define NJOB 13                // seq-source interaction jobs
#define NCHB 400               // bucketing chunks per field
#define CHUNK 512              // incidences per chunk (400*512 = 204800)
#define SLOTS 640              // fixed region per bucket (max bucket ~510, +6.4 sd headroom)
#define DIAG_REPS 8

typedef float f32x4 __attribute__((ext_vector_type(4)));

// ws byte offsets
#define WS_ENT   0x000000ULL   // 2*500*640*4 = 2,560,000
#define WS_CNT   0x280000ULL   // 2*500*400*4 = 1,600,000
#define WS_OFF   0x420000ULL   // 1,600,000
#define WS_TOT   0x5C0000ULL   // 2*500*4
#define WS_PART  0x5D0000ULL   // 28*4*4096*4 = 1,835,008
#define WS_Q     0x7A0000ULL   // 4096*64*4 = 1,048,576
#define WS_PART2 0x8B0000ULL   // 1,835,008 (diag scratch)
#define WS_NEED  0xA80000ULL

// triu_indices(8, k=1) order
__device__ const int PA[NPAIR] = {0,0,0,0,0,0,0, 1,1,1,1,1,1, 2,2,2,2,2, 3,3,3,3, 4,4,4, 5,5, 6};
__device__ const int PB[NPAIR] = {1,2,3,4,5,6,7, 2,3,4,5,6,7, 3,4,5,6,7, 4,5,6,7, 5,6,7, 6,7, 7};

__device__ __forceinline__ int job_s(int j)    { return (j < 7) ? 0 : 1; }
__device__ __forceinline__ int job_c(int j)    { return (j == 0) ? 1 : ((j < 7) ? j + 1 : j - 5); }
__device__ __forceinline__ int job_pidx(int j) { return (j < 7) ? job_c(j) - 1 : job_c(j) + 5; }

// ---- phase 1: per-chunk bucket counts (LDS histogram) + fold in part-zeroing ----
__global__ __launch_bounds__(256) void countk(const int* __restrict__ x_seq,
                                              unsigned* __restrict__ cnt,
                                              float* __restrict__ part)
{
    __shared__ unsigned h[NSLAB];
    int blk = blockIdx.x;                    // 0..799
    int s = blk / NCHB, ch = blk - s * NCHB;
    for (int k = threadIdx.x; k < NSLAB; k += 256) h[k] = 0u;
    __syncthreads();
    int base = s * NIDXF + ch * CHUNK;
    #pragma unroll
    for (int it = 0; it < CHUNK / 256; ++it) {
        int v = x_seq[base + it * 256 + threadIdx.x];
        atomicAdd(&h[v / SLAB_ROWS], 1u);
    }
    __syncthreads();
    // transposed layout: cnt[(s*NSLAB + bkt)*NCHB + ch]
    for (int k = threadIdx.x; k < NSLAB; k += 256)
        cnt[((size_t)s * NSLAB + k) * NCHB + ch] = h[k];
    // zero the partial accumulator (574 floats per block covers 458,752)
    int z0 = blk * 574;
    for (int k = z0 + threadIdx.x; k < z0 + 574 && k < NPAIR * 4 * BQ; k += 256)
        part[k] = 0.0f;
}

// ---- phase 2: per-bucket exclusive scan over chunks (wave per bucket) + totals ----
__global__ __launch_bounds__(256) void offk(const unsigned* __restrict__ cnt,
                                            unsigned* __restrict__ off,
                                            unsigned* __restrict__ tot)
{
    int lane = threadIdx.x & 63;
    int bid = blockIdx.x * 4 + (threadIdx.x >> 6);   // 0..999
    int s = bid / NSLAB, bkt = bid - s * NSLAB;
    const unsigned* c = cnt + ((size_t)s * NSLAB + bkt) * NCHB;
    unsigned* o = off + ((size_t)s * NSLAB + bkt) * NCHB;
    unsigned carry = 0u;
    #pragma unroll
    for (int p = 0; p < 7; ++p) {                    // 7*64 = 448 >= 400
        int idx = p * 64 + lane;
        unsigned v = (idx < NCHB) ? c[idx] : 0u;
        unsigned inc = v;
        #pragma unroll
        for (int d = 1; d < 64; d <<= 1) {
            unsigned t = __shfl_up(inc, d, 64);
            if (lane >= d) inc += t;
        }
        if (idx < NCHB) o[idx] = carry + inc - v;
        carry += __shfl(inc, 63, 64);
    }
    if (lane == 0) tot[bid] = carry;
}

// ---- phase 3: scatter packed (v,b) entries into fixed 640-slot bucket regions ----
__global__ __launch_bounds__(256) void scatterk(const int* __restrict__ x_seq,
                                                const unsigned* __restrict__ off,
                                                unsigned* __restrict__ ent)
{
    __shared__ unsigned cur[NSLAB];
    int blk = blockIdx.x;
    int s = blk / NCHB, ch = blk - s * NCHB;
    for (int k = threadIdx.x; k < NSLAB; k += 256)
        cur[k] = off[((size_t)s * NSLAB + k) * NCHB + ch];
    __syncthreads();
    #pragma unroll
    for (int it = 0; it < CHUNK / 256; ++it) {
        int i = ch * CHUNK + it * 256 + threadIdx.x;
        int v = x_seq[s * NIDXF + i];
        int b = i / LQ;
        int bkt = v / SLAB_ROWS;
        unsigned pos = atomicAdd(&cur[bkt], 1u);     // LDS atomic
        ent[((size_t)s * NSLAB + bkt) * SLOTS + pos] = ((unsigned)v << 12) | (unsigned)b;
    }
}

// ---- phase 4: pooled P_10 (Q for job 0) ----
__global__ __launch_bounds__(256) void qbuild(const int* __restrict__ x_seq,
                                              const float* __restrict__ tables,
                                              float* __restrict__ Q)
{
    int lane = threadIdx.x & 63, w = threadIdx.x >> 6;
    int b = blockIdx.x * 4 + w;
    const float* __restrict__ tab = tables + (size_t)(1 * FQ + 0) * VQ * EQ;  // T_{1->0}
    const int* __restrict__ xs = x_seq + NIDXF + b * LQ;                      // field 1
    float acc = 0.0f;
    #pragma unroll 10
    for (int l = 0; l < LQ; ++l)
        acc += tab[(size_t)xs[l] * EQ + lane];
    Q[(size_t)b * EQ + lane] = acc * (1.0f / LQ);
}

// ---- phase 5 body: slab interaction (512 thr, LDS x_cat, prefetched entries) ----
__device__ __forceinline__ void interact_body(
    int job, int sl,
    const float* __restrict__ tables, const float* __restrict__ Q,
    const int* __restrict__ x_cat, const unsigned* __restrict__ ent,
    const unsigned* __restrict__ tot, float* __restrict__ part)
{
    __shared__ float slab[SLAB_ROWS * EQ];   // 51.2 KB
    __shared__ int   xc[BQ];                 // 16 KB (cat-target jobs)
    int s = job_s(job), c = job_c(job), pidx = job_pidx(job);
    int tid = threadIdx.x;

    const float* __restrict__ tab =
        tables + ((size_t)s * FQ + c) * VQ * EQ + (size_t)sl * SLAB_ROWS * EQ;
    for (int t = tid; t < SLAB_ROWS * EQ / 4; t += 512) {
        int lw = t * 4;
        int v = lw >> 6, wd = lw & 63;
        f32x4 val = __builtin_nontemporal_load((const f32x4*)(tab + lw));
        *(f32x4*)&slab[v * EQ + (wd ^ ((v & 7) << 2))] = val;   // bank-deswizzle
    }
    if (job != 0)
        for (int k = tid; k < BQ; k += 512)
            xc[k] = x_cat[(size_t)(c - 2) * BQ + k];
    __syncthreads();

    unsigned n = tot[s * NSLAB + sl];
    const unsigned* __restrict__ e = ent + ((size_t)s * NSLAB + sl) * SLOTS;
    const float* __restrict__ qtab = tables + ((size_t)c * FQ + s) * VQ * EQ;  // T_{c->s}
    int gid = tid >> 2, sub = tid & 3;       // 128 groups of 4 lanes
    const float scl = 1.0f / LQ;

    unsigned k = (unsigned)gid;
    if (k < n) {
        unsigned ev = e[k];
        int b = (int)(ev & 4095u);
        int r = (int)(ev >> 12) - sl * SLAB_ROWS;
        const float* qp = (job == 0) ? (Q + (size_t)b * EQ)
                                     : (qtab + (size_t)xc[b] * EQ);
        while (true) {
            int ew = sub * 16;
            f32x4 q0 = *(const f32x4*)(qp + ew);
            f32x4 q1 = *(const f32x4*)(qp + ew + 4);
            f32x4 q2 = *(const f32x4*)(qp + ew + 8);
            f32x4 q3 = *(const f32x4*)(qp + ew + 12);
            // prefetch next entry metadata while q-loads are in flight
            unsigned kn = k + 128;
            bool hn = kn < n;
            int bn = 0, rn = 0; const float* qpn = nullptr;
            if (hn) {
                unsigned evn = e[kn];
                bn = (int)(evn & 4095u);
                rn = (int)(evn >> 12) - sl * SLAB_ROWS;
                qpn = (job == 0) ? (Q + (size_t)bn * EQ)
                                 : (qtab + (size_t)xc[bn] * EQ);
            }
            f32x4 r0 = *(const f32x4*)&slab[r * EQ + ((ew)      ^ ((r & 7) << 2))];
            f32x4 r1 = *(const f32x4*)&slab[r * EQ + ((ew + 4)  ^ ((r & 7) << 2))];
            f32x4 r2 = *(const f32x4*)&slab[r * EQ + ((ew + 8)  ^ ((r & 7) << 2))];
            f32x4 r3 = *(const f32x4*)&slab[r * EQ + ((ew + 12) ^ ((r & 7) << 2))];
            float p = q0.x*r0.x + q0.y*r0.y + q0.z*r0.z + q0.w*r0.w
                    + q1.x*r1.x + q1.y*r1.y + q1.z*r1.z + q1.w*r1.w
                    + q2.x*r2.x + q2.y*r2.y + q2.z*r2.z + q2.w*r2.w
                    + q3.x*r3.x + q3.y*r3.y + q3.z*r3.z + q3.w*r3.w;
            p += __shfl_xor(p, 1, 64);
            p += __shfl_xor(p, 2, 64);
            if (sub == 0)
                atomicAdd(&part[((size_t)pidx * 4 + (sl & 3)) * BQ + b], p * scl);
            if (!hn) break;
            k = kn; b = bn; r = rn; qp = qpn;
        }
    }
}

__global__ __launch_bounds__(512) void interactk(
    const float* __restrict__ tables, const float* __restrict__ Q,
    const int* __restrict__ x_cat, const unsigned* __restrict__ ent,
    const unsigned* __restrict__ tot, float* __restrict__ part)
{
    int job = blockIdx.x / NSLAB, sl = blockIdx.x - job * NSLAB;
    interact_body(job, sl, tables, Q, x_cat, ent, tot, part);
}

// sacrificial diagnostic: 8 rep-major repeats -> >1ms dispatch -> rocprof top-5
__global__ __launch_bounds__(512) void interact_diag(
    const float* __restrict__ tables, const float* __restrict__ Q,
    const int* __restrict__ x_cat, const unsigned* __restrict__ ent,
    const unsigned* __restrict__ tot, float* __restrict__ part2)
{
    int u = blockIdx.x % (NJOB * NSLAB);     // rep-major: rep = blockIdx.x / 6500
    int job = u / NSLAB, sl = u - job * NSLAB;
    interact_body(job, sl, tables, Q, x_cat, ent, tot, part2);
}

// ---- phase 6: cat-cat pairs ----
__global__ __launch_bounds__(256) void catcatk(const int* __restrict__ x_cat,
                                               const float* __restrict__ tables,
                                               float* __restrict__ part)
{
    int p     = 13 + blockIdx.x / (BQ / 4);
    int chunk = blockIdx.x % (BQ / 4);
    int lane = threadIdx.x & 63, w = threadIdx.x >> 6;
    int b = chunk * 4 + w;
    int a = PA[p], c = PB[p];
    int va_i = x_cat[(size_t)(a - 2) * BQ + b];
    int vc_i = x_cat[(size_t)(c - 2) * BQ + b];
    float va = tables[((size_t)a * FQ + c) * VQ * EQ + (size_t)va_i * EQ + lane];
    float vc = tables[((size_t)c * FQ + a) * VQ * EQ + (size_t)vc_i * EQ + lane];
    float pr = va * vc;
    #pragma unroll
    for (int off = 32; off; off >>= 1)
        pr += __shfl_down(pr, off, 64);
    if (lane == 0) part[((size_t)p * 4 + 0) * BQ + b] = pr;
}

// ---- phase 7: final reduce ----
__global__ __launch_bounds__(256) void reducek(const float* __restrict__ part,
                                               float* __restrict__ out)
{
    int b = blockIdx.x * 256 + threadIdx.x;
    if (b < BQ) {
        float sum = 0.0f;
        #pragma unroll
        for (int q = 0; q < NPAIR * 4; ++q)
            sum += part[(size_t)q * BQ + b];
        out[b] = sum;
    }
}

// ---- fallback (R2 path, known-correct) ----
__global__ __launch_bounds__(256) void fb_pair_dot(const int* __restrict__ x_seq,
                                                   const int* __restrict__ x_cat,
                                                   const float* __restrict__ tables,
                                                   float* __restrict__ out)
{
    const int pair  = blockIdx.x / (BQ / 4);
    const int chunk = blockIdx.x % (BQ / 4);
    const int b0 = chunk * 4;
    const int a = PA[pair], c = PB[pair];
    const int tid = threadIdx.x, lane = tid & 63, wave = tid >> 6;
    const int b = b0 + wave;
    __shared__ int sidx[2][4][LQ];
    if (a < NSEQ && tid < 4 * LQ) {
        int bl = tid / LQ, l = tid - bl * LQ;
        sidx[0][bl][l] = x_seq[((size_t)a * BQ + b0 + bl) * LQ + l];
    }
    if (c < NSEQ && tid < 4 * LQ) {
        int bl = tid / LQ, l = tid - bl * LQ;
        sidx[1][bl][l] = x_seq[((size_t)c * BQ + b0 + bl) * LQ + l];
    }
    if (a < NSEQ || c < NSEQ) __syncthreads();
    const float* tab1 = tables + ((size_t)a * FQ + c) * VQ * EQ;
    const float* tab2 = tables + ((size_t)c * FQ + a) * VQ * EQ;
    float va, vc;
    if (a < NSEQ) {
        float acc = 0.0f;
        for (int l = 0; l < LQ; ++l) acc += tab1[(size_t)sidx[0][wave][l] * EQ + lane];
        va = acc * (1.0f / LQ);
    } else va = tab1[(size_t)x_cat[(size_t)(a - NSEQ) * BQ + b] * EQ + lane];
    if (c < NSEQ) {
        float acc = 0.0f;
        for (int l = 0; l < LQ; ++l) acc += tab2[(size_t)sidx[1][wave][l] * EQ + lane];
        vc = acc * (1.0f / LQ);
    } else vc = tab2[(size_t)x_cat[(size_t)(c - NSEQ) * BQ + b] * EQ + lane];
    float prod = va * vc;
    #pragma unroll
    for (int off = 32; off; off >>= 1) prod += __shfl_down(prod, off, 64);
    if (lane == 0) atomicAdd(&out[b], prod);
}

__global__ __launch_bounds__(256) void fb_zero(float* __restrict__ out)
{
    int b = blockIdx.x * 256 + threadIdx.x;
    if (b < BQ) out[b] = 0.0f;
}

extern "C" void kernel_launch(void* const* d_in, const int* in_sizes, int n_in,
                              void* d_out, int out_size, void* d_ws, size_t ws_size,
                              hipStream_t stream) {
    const int*   x_seq  = (const int*)d_in[0];
    const int*   x_cat  = (const int*)d_in[1];
    const float* tables = (const float*)d_in[2];
    float*       out    = (float*)d_out;

    if (ws_size >= WS_NEED) {
        unsigned* ent  = (unsigned*)((char*)d_ws + WS_ENT);
        unsigned* cnt  = (unsigned*)((char*)d_ws + WS_CNT);
        unsigned* off  = (unsigned*)((char*)d_ws + WS_OFF);
        unsigned* tot  = (unsigned*)((char*)d_ws + WS_TOT);
        float*    part = (float*)   ((char*)d_ws + WS_PART);
        float*    Q    = (float*)   ((char*)d_ws + WS_Q);
        float*    part2= (float*)   ((char*)d_ws + WS_PART2);

        countk  <<<2 * NCHB, 256, 0, stream>>>(x_seq, cnt, part);
        offk    <<<2 * NSLAB / 4, 256, 0, stream>>>(cnt, off, tot);
        scatterk<<<2 * NCHB, 256, 0, stream>>>(x_seq, off, ent);
        qbuild  <<<BQ / 4, 256, 0, stream>>>(x_seq, tables, Q);
        interactk<<<NJOB * NSLAB, 512, 0, stream>>>(tables, Q, x_cat, ent, tot, part);
        catcatk <<<15 * (BQ / 4), 256, 0, stream>>>(x_cat, tables, part);
        reducek <<<(BQ + 255) / 256, 256, 0, stream>>>(part, out);
        // sacrificial diagnostic (counters visibility); writes only part2 scratch
        interact_diag<<<DIAG_REPS * NJOB * NSLAB, 512, 0, stream>>>(
            tables, Q, x_cat, ent, tot, part2);
    } else {
        fb_zero<<<(BQ + 255) / 256, 256, 0, stream>>>(out);
        fb_pair_dot<<<NPAIR * (BQ / 4), 256, 0, stream>>>(x_seq, x_cat, tables, out);
    }
}

// Round 8
// 117.469 us; speedup vs baseline: 10.1898x; 10.1898x over previous
//
#include <hip/hip_runtime.h>

// Problem constants (match reference)
#define FQ 8
#define NSEQ 2
#define BQ 4096
#define LQ 50
#define VQ 100000
#define EQ 64
#define NPAIR 28
#define CQ 4               // batch elems per block (1 per wave)
#define CHUNKS (BQ / CQ)   // 1024 blocks per pair

typedef float f32x4 __attribute__((ext_vector_type(4)));

// triu_indices(8, k=1) order
__device__ const int PA[NPAIR] = {0,0,0,0,0,0,0, 1,1,1,1,1,1, 2,2,2,2,2, 3,3,3,3, 4,4,4, 5,5, 6};
__device__ const int PB[NPAIR] = {1,2,3,4,5,6,7, 2,3,4,5,6,7, 3,4,5,6,7, 4,5,6,7, 5,6,7, 6,7, 7};

__device__ __forceinline__ f32x4 shflxor4(f32x4 v, int m) {
    f32x4 r;
    r.x = __shfl_xor(v.x, m, 64);
    r.y = __shfl_xor(v.y, m, 64);
    r.z = __shfl_xor(v.z, m, 64);
    r.w = __shfl_xor(v.w, m, 64);
    return r;
}
__device__ __forceinline__ float dot4(f32x4 a, f32x4 b) {
    return a.x*b.x + a.y*b.y + a.z*b.z + a.w*b.w;
}

// R2 structure, but each 256B table row is loaded as 16 lanes x float4
// (4 rows per wave-VMEM instruction instead of 1). Lane = (grp, sub):
// grp = lane>>4 pools a strided quarter of the 50 draws; sub = lane&15
// owns row elements [4*sub, 4*sub+4).
template <bool ATOMIC>
__global__ __launch_bounds__(256) void pair_pool_dot4(
    const int* __restrict__ x_seq,    // [2, B, L]
    const int* __restrict__ x_cat,    // [6, B, 1]
    const float* __restrict__ tables, // [8, 8, V, E]
    float* __restrict__ partial,      // [NPAIR, B] (ws path)
    float* __restrict__ out)          // [B] (atomic path)
{
    const int blk   = blockIdx.x;
    const int pair  = blk / CHUNKS;
    const int chunk = blk - pair * CHUNKS;
    const int b0    = chunk * CQ;
    const int a = PA[pair], c = PB[pair];   // a < c
    const int tid  = threadIdx.x;
    const int lane = tid & 63;
    const int wave = tid >> 6;
    const int sub  = lane & 15;
    const int grp  = lane >> 4;
    const int b    = b0 + wave;

    __shared__ int sidx[2][CQ][LQ];

    if (a < NSEQ && tid < CQ * LQ) {
        int bl = tid / LQ, l = tid - bl * LQ;
        sidx[0][bl][l] = x_seq[((size_t)a * BQ + b0 + bl) * LQ + l];
    }
    if (c < NSEQ && tid < CQ * LQ) {
        int bl = tid / LQ, l = tid - bl * LQ;
        sidx[1][bl][l] = x_seq[((size_t)c * BQ + b0 + bl) * LQ + l];
    }
    if (a < NSEQ || c < NSEQ) __syncthreads();

    const float* __restrict__ tab1 = tables + ((size_t)a * FQ + c) * VQ * EQ; // a -> c
    const float* __restrict__ tab2 = tables + ((size_t)c * FQ + a) * VQ * EQ; // c -> a

    float result;
    if (c < NSEQ) {
        // pair (0,1): both sequence fields
        f32x4 A = {0.f, 0.f, 0.f, 0.f}, B = {0.f, 0.f, 0.f, 0.f};
        for (int l = grp; l < LQ; l += 4)
            A += *(const f32x4*)(tab1 + (size_t)sidx[0][wave][l] * EQ + sub * 4);
        for (int l = grp; l < LQ; l += 4)
            B += *(const f32x4*)(tab2 + (size_t)sidx[1][wave][l] * EQ + sub * 4);
        // merge the 4 group-partials so every group holds the full pooled vectors
        A += shflxor4(A, 16);  A += shflxor4(A, 32);
        B += shflxor4(B, 16);  B += shflxor4(B, 32);
        float p = dot4(A, B);
        p += __shfl_xor(p, 1, 64);
        p += __shfl_xor(p, 2, 64);
        p += __shfl_xor(p, 4, 64);
        p += __shfl_xor(p, 8, 64);
        result = p * (1.0f / (LQ * LQ));
    } else if (a < NSEQ) {
        // seq x cat: Σ_g dot(A_g, C) = dot(Σ_g A_g, C) — no cross-group merge needed
        f32x4 A = {0.f, 0.f, 0.f, 0.f};
        for (int l = grp; l < LQ; l += 4)
            A += *(const f32x4*)(tab1 + (size_t)sidx[0][wave][l] * EQ + sub * 4);
        int vq = x_cat[(size_t)(c - NSEQ) * BQ + b];
        f32x4 C = *(const f32x4*)(tab2 + (size_t)vq * EQ + sub * 4);
        float p = dot4(A, C);
        p += __shfl_xor(p, 1, 64);
        p += __shfl_xor(p, 2, 64);
        p += __shfl_xor(p, 4, 64);
        p += __shfl_xor(p, 8, 64);
        p += __shfl_xor(p, 16, 64);
        p += __shfl_xor(p, 32, 64);
        result = p * (1.0f / LQ);
    } else {
        // cat x cat: one row each side; groups redundantly load the same
        // cachelines (hardware-coalesced), reduce within one group's 16 lanes
        int va_i = x_cat[(size_t)(a - NSEQ) * BQ + b];
        int vc_i = x_cat[(size_t)(c - NSEQ) * BQ + b];
        f32x4 A = *(const f32x4*)(tab1 + (size_t)va_i * EQ + sub * 4);
        f32x4 C = *(const f32x4*)(tab2 + (size_t)vc_i * EQ + sub * 4);
        float p = dot4(A, C);
        p += __shfl_xor(p, 1, 64);
        p += __shfl_xor(p, 2, 64);
        p += __shfl_xor(p, 4, 64);
        p += __shfl_xor(p, 8, 64);
        result = p;
    }

    if (lane == 0) {
        if (ATOMIC) atomicAdd(&out[b], result);
        else        partial[(size_t)pair * BQ + b] = result;
    }
}

__global__ __launch_bounds__(256) void reduce_pairs(
    const float* __restrict__ partial, float* __restrict__ out)
{
    int b = blockIdx.x * 256 + threadIdx.x;
    if (b < BQ) {
        float s = 0.0f;
        #pragma unroll
        for (int p = 0; p < NPAIR; ++p)
            s += partial[(size_t)p * BQ + b];
        out[b] = s;
    }
}

__global__ __launch_bounds__(256) void zero_out(float* __restrict__ out)
{
    int b = blockIdx.x * 256 + threadIdx.x;
    if (b < BQ) out[b] = 0.0f;
}

extern "C" void kernel_launch(void* const* d_in, const int* in_sizes, int n_in,
                              void* d_out, int out_size, void* d_ws, size_t ws_size,
                              hipStream_t stream) {
    const int*   x_seq  = (const int*)d_in[0];
    const int*   x_cat  = (const int*)d_in[1];
    const float* tables = (const float*)d_in[2];
    float*       out    = (float*)d_out;

    const size_t need = (size_t)NPAIR * BQ * sizeof(float);
    if (ws_size >= need) {
        float* partial = (float*)d_ws;
        pair_pool_dot4<false><<<NPAIR * CHUNKS, 256, 0, stream>>>(
            x_seq, x_cat, tables, partial, out);
        reduce_pairs<<<(BQ + 255) / 256, 256, 0, stream>>>(partial, out);
    } else {
        zero_out<<<(BQ + 255) / 256, 256, 0, stream>>>(out);
        pair_pool_dot4<true><<<NPAIR * CHUNKS, 256, 0, stream>>>(
            x_seq, x_cat, tables, nullptr, out);
    }
}